// Round 12
// baseline (121.866 us; speedup 1.0000x reference)
//
#include <hip/hip_runtime.h>

#define B_SZ 32
#define L_SZ 512
#define D_SZ 256
#define FRAMES_PER_WAVE 8
#define FRAMES_PER_BLOCK 32    // 4 waves x 8 frames
#define REP 4                  // DIAGNOSTIC: repeat body to surface kernel in rocprof top-5

// clang-native vector types (required by __builtin_nontemporal_*)
typedef float f4 __attribute__((ext_vector_type(4)));
typedef int   i4 __attribute__((ext_vector_type(4)));

// Output-centric gather (round-10 structure), body repeated REP times.
// Reps are idempotent (same values rewritten); the compiler cannot eliminate
// earlier reps across the asm memory barrier. Dispatch duration ~= REP * K,
// large enough to crack the rocprof top-5 and give us the kernel's own
// counters (WRITE_SIZE, FETCH_SIZE, VALUBusy, Occupancy) for the first time.
__global__ void __launch_bounds__(256)
lr_gather_kernel(const float* __restrict__ hidden,
                 const int* __restrict__ durations,
                 float* __restrict__ out,
                 int maxT, int chunks) {
    const int lane  = threadIdx.x & 63;
    const int wv    = threadIdx.x >> 6;
    const int bid   = blockIdx.x;
    const int b     = bid / chunks;             // consecutive bids sweep one batch
    const int chunk = bid - b * chunks;
    const int t0    = chunk * FRAMES_PER_BLOCK + wv * FRAMES_PER_WAVE;
    if (t0 >= maxT) return;                     // wave-uniform

    // duration row: lane i holds durs[8i .. 8i+7]
    const i4* drow = (const i4*)(durations + b * L_SZ);
    const i4 a = drow[lane * 2];
    const i4 c = drow[lane * 2 + 1];
    const int s = a.x + a.y + a.z + a.w + c.x + c.y + c.z + c.w;    // <= 56
    const int packed = a.x | (a.y << 3) | (a.z << 6) | (a.w << 9)
                     | (c.x << 12) | (c.y << 15) | (c.z << 18) | (c.w << 21);

    // inclusive scan of per-lane sums across the wave
    int incl = s;
    #pragma unroll
    for (int off = 1; off < 64; off <<= 1) {
        const int tt = __shfl_up(incl, off, 64);
        if (lane >= off) incl += tt;
    }
    const int ex = incl - s;    // exclusive prefix: start frame of lane's rows

    const float* hbase = hidden + (size_t)b * L_SZ * D_SZ;
    float*       obase = out    + (size_t)b * maxT * D_SZ;
    const f4 z = (f4){0.f, 0.f, 0.f, 0.f};

    #pragma unroll 1
    for (int rep = 0; rep < REP; ++rep) {
        #pragma unroll
        for (int f = 0; f < FRAMES_PER_WAVE; ++f) {
            const int t = t0 + f;
            if (t >= maxT) break;               // wave-uniform
            const unsigned long long mask = __ballot(incl > t);
            f4 v = z;
            if (mask) {                         // t < total: find owning row
                const int l    = __ffsll(mask) - 1;    // first lane covering t
                const int base = __shfl(ex, l, 64);
                const int pk   = __shfl(packed, l, 64);
                int acc = base, r = 0;
                #pragma unroll
                for (int k = 0; k < 7; ++k) {   // count incl prefixes <= t
                    acc += (pk >> (3 * k)) & 7;
                    r += (acc <= t);
                }
                const int row = l * 8 + r;      // phoneme index for frame t
                v = *((const f4*)(hbase + (size_t)row * D_SZ) + lane);
            }
            __builtin_nontemporal_store(v, (f4*)(obase + (size_t)t * D_SZ) + lane);
        }
        asm volatile("" ::: "memory");          // forbid cross-rep store dedup
    }
}

extern "C" void kernel_launch(void* const* d_in, const int* in_sizes, int n_in,
                              void* d_out, int out_size, void* d_ws, size_t ws_size,
                              hipStream_t stream) {
    const float* hidden = (const float*)d_in[0];
    const int* durations = (const int*)d_in[1];
    float* out = (float*)d_out;

    const int maxT   = out_size / (B_SZ * D_SZ);
    const int chunks = (maxT + FRAMES_PER_BLOCK - 1) / FRAMES_PER_BLOCK;

    lr_gather_kernel<<<B_SZ * chunks, 256, 0, stream>>>(hidden, durations, out,
                                                        maxT, chunks);
}

// Round 13
// 89.420 us; speedup vs baseline: 1.3628x; 1.3628x over previous
//
#include <hip/hip_runtime.h>

#define B_SZ 32
#define L_SZ 512
#define D_SZ 256
#define FRAMES_PER_WAVE 8
#define FRAMES_PER_BLOCK 32    // 4 waves x 8 frames

// clang-native vector types (required by __builtin_nontemporal_*)
typedef float f4 __attribute__((ext_vector_type(4)));
typedef int   i4 __attribute__((ext_vector_type(4)));

// Output-centric gather: wave owns 8 consecutive OUTPUT frames of batch b.
// Measured via REP=4 diagnostic (round 12): single-pass ~14.8 us, WRITE_SIZE
// exactly = output (62.6 MB, no RFO/write-amp), ~4.3 TB/s during dispatch —
// ~85% of the 12.5 us traffic roofline. Total dur_us is dominated by
// harness-fixed work (poison fill ~43.5 us + ~28 us dispatch swarm).
// Row lookup all-register: ballot over lane-scan + 2 shfl + 7-step packed-dur
// walk. Pad frames fall out as mask==0 -> store zeros. No LDS, no barriers,
// no conditional stores.
__global__ void __launch_bounds__(256)
lr_gather_kernel(const float* __restrict__ hidden,
                 const int* __restrict__ durations,
                 float* __restrict__ out,
                 int maxT, int chunks) {
    const int lane  = threadIdx.x & 63;
    const int wv    = threadIdx.x >> 6;
    const int bid   = blockIdx.x;
    const int b     = bid / chunks;             // consecutive bids sweep one batch
    const int chunk = bid - b * chunks;
    const int t0    = chunk * FRAMES_PER_BLOCK + wv * FRAMES_PER_WAVE;
    if (t0 >= maxT) return;                     // wave-uniform

    // duration row: lane i holds durs[8i .. 8i+7]
    const i4* drow = (const i4*)(durations + b * L_SZ);
    const i4 a = drow[lane * 2];
    const i4 c = drow[lane * 2 + 1];
    const int s = a.x + a.y + a.z + a.w + c.x + c.y + c.z + c.w;    // <= 56
    const int packed = a.x | (a.y << 3) | (a.z << 6) | (a.w << 9)
                     | (c.x << 12) | (c.y << 15) | (c.z << 18) | (c.w << 21);

    // inclusive scan of per-lane sums across the wave
    int incl = s;
    #pragma unroll
    for (int off = 1; off < 64; off <<= 1) {
        const int tt = __shfl_up(incl, off, 64);
        if (lane >= off) incl += tt;
    }
    const int ex = incl - s;    // exclusive prefix: start frame of lane's rows

    const float* hbase = hidden + (size_t)b * L_SZ * D_SZ;
    float*       obase = out    + (size_t)b * maxT * D_SZ;
    const f4 z = (f4){0.f, 0.f, 0.f, 0.f};

    #pragma unroll
    for (int f = 0; f < FRAMES_PER_WAVE; ++f) {
        const int t = t0 + f;
        if (t >= maxT) break;                   // wave-uniform
        const unsigned long long mask = __ballot(incl > t);
        f4 v = z;
        if (mask) {                             // t < total: find owning row
            const int l    = __ffsll(mask) - 1;        // first lane covering t
            const int base = __shfl(ex, l, 64);
            const int pk   = __shfl(packed, l, 64);
            int acc = base, r = 0;
            #pragma unroll
            for (int k = 0; k < 7; ++k) {       // count incl prefixes <= t
                acc += (pk >> (3 * k)) & 7;
                r += (acc <= t);
            }
            const int row = l * 8 + r;          // phoneme index for frame t
            v = *((const f4*)(hbase + (size_t)row * D_SZ) + lane);  // cached: d-fold reuse
        }
        __builtin_nontemporal_store(v, (f4*)(obase + (size_t)t * D_SZ) + lane);
    }
}

extern "C" void kernel_launch(void* const* d_in, const int* in_sizes, int n_in,
                              void* d_out, int out_size, void* d_ws, size_t ws_size,
                              hipStream_t stream) {
    const float* hidden = (const float*)d_in[0];
    const int* durations = (const int*)d_in[1];
    float* out = (float*)d_out;

    const int maxT   = out_size / (B_SZ * D_SZ);
    const int chunks = (maxT + FRAMES_PER_BLOCK - 1) / FRAMES_PER_BLOCK;

    lr_gather_kernel<<<B_SZ * chunks, 256, 0, stream>>>(hidden, durations, out,
                                                        maxT, chunks);
}